// Round 10
// baseline (294.765 us; speedup 1.0000x reference)
//
#include <hip/hip_runtime.h>
#include <hip/hip_bf16.h>

typedef __bf16 bf16;
typedef __bf16 bf16x4 __attribute__((ext_vector_type(4)));
typedef __bf16 bf16x8 __attribute__((ext_vector_type(8)));
typedef float  f32x4  __attribute__((ext_vector_type(4)));

#define AS1 __attribute__((address_space(1)))
#define AS3 __attribute__((address_space(3)))

__device__ __forceinline__ void gload_lds16(const bf16* g, bf16* l) {
    __builtin_amdgcn_global_load_lds((const AS1 void*)g, (AS3 void*)l, 16, 0, 0);
}

__device__ __forceinline__ bf16x8 pack8(const float4 a, const float4 b) {
    bf16x8 o;
    o[0] = (bf16)a.x; o[1] = (bf16)a.y; o[2] = (bf16)a.z; o[3] = (bf16)a.w;
    o[4] = (bf16)b.x; o[5] = (bf16)b.y; o[6] = (bf16)b.z; o[7] = (bf16)b.w;
    return o;
}

// ---------------------------------------------------------------------------
// proj9: x(f32) @ {Wq,Wlk,Wlv}(f32)^T with convert-on-stage (cvt5 deleted).
// 128x64 tiles, BK=64, XOR-64 swizzled LDS (element (row,k) at
// row*64 + ((k/8)^(row&7))*8 + k%8 -- same contract as the R8-verified core).
// Reg-staging (12 float4/thread) lets us write the swizzle directly; T14
// split: global loads issued BEFORE compute, cvt+ds_write after (HBM latency
// hides under 16 MFMAs + 12 ds_reads). grid=(48,16): bx<32 -> Q (PRE-SCALED
// by 1/sqrt(128)*log2e), 32..39 -> LK, 40..47 -> LVt[hd=512][T=2048].
// ---------------------------------------------------------------------------
__global__ __launch_bounds__(256, 3) void proj9(
    const float* __restrict__ x, const float* __restrict__ Wq,
    const float* __restrict__ Wlk, const float* __restrict__ Wlv,
    bf16* __restrict__ Q, bf16* __restrict__ LK, bf16* __restrict__ LVt)
{
    __shared__ __align__(16) bf16 As[2][128 * 64];  // 16 KB each
    __shared__ __align__(16) bf16 Bs[2][64 * 64];   //  8 KB each

    const int bx = blockIdx.x, by = blockIdx.y;
    const int tid = threadIdx.x, lane = tid & 63, wave = tid >> 6;
    const int wm = wave * 32;
    const int r16 = lane & 15, q8 = lane >> 4;
    const int k7 = r16 & 7;

    const float* Bp; int n0;
    if (bx < 32)      { Bp = Wq;  n0 = bx * 64; }
    else if (bx < 40) { Bp = Wlk; n0 = (bx - 32) * 64; }
    else              { Bp = Wlv; n0 = (bx - 40) * 64; }

    // staging coords: row-in-round s (32 rows/round), k-chunk c; source chunk
    // pre-swizzled by row&7 so LDS chunk c holds global chunk c^(row&7).
    const int s = tid >> 3, c = tid & 7;
    const int gqe = (c ^ (s & 7)) * 8;
    const float* aSrc = x  + (size_t)(by * 128 + s) * 2048 + gqe;
    const float* bSrc = Bp + (size_t)(n0 + s) * 2048 + gqe;

    f32x4 acc[2][4] = {};
    float4 ra[4][2], rb[2][2];

    auto loads = [&](int kt) {
#pragma unroll
        for (int j = 0; j < 4; ++j) {
            const float* p = aSrc + (size_t)j * 32 * 2048 + kt;
            ra[j][0] = *(const float4*)p;
            ra[j][1] = *(const float4*)(p + 4);
        }
#pragma unroll
        for (int j = 0; j < 2; ++j) {
            const float* p = bSrc + (size_t)j * 32 * 2048 + kt;
            rb[j][0] = *(const float4*)p;
            rb[j][1] = *(const float4*)(p + 4);
        }
    };
    auto writes = [&](int buf) {
#pragma unroll
        for (int j = 0; j < 4; ++j)
            *(bf16x8*)&As[buf][(j * 32 + s) * 64 + c * 8] = pack8(ra[j][0], ra[j][1]);
#pragma unroll
        for (int j = 0; j < 2; ++j)
            *(bf16x8*)&Bs[buf][(j * 32 + s) * 64 + c * 8] = pack8(rb[j][0], rb[j][1]);
    };

    loads(0); writes(0);
    __syncthreads();

    int cur = 0;
    for (int kt = 0; kt < 2048; kt += 64) {
        const bool pf = (kt + 64 < 2048);
        if (pf) loads(kt + 64);          // issue early (T14)

        bf16x8 a[2][2], b[4][2];
#pragma unroll
        for (int r = 0; r < 2; ++r)
#pragma unroll
            for (int kc = 0; kc < 2; ++kc)
                a[r][kc] = *(const bf16x8*)&As[cur][(wm + r * 16 + r16) * 64
                                                   + ((kc * 4 + q8) ^ k7) * 8];
#pragma unroll
        for (int cc = 0; cc < 4; ++cc)
#pragma unroll
            for (int kc = 0; kc < 2; ++kc)
                b[cc][kc] = *(const bf16x8*)&Bs[cur][(cc * 16 + r16) * 64
                                                    + ((kc * 4 + q8) ^ k7) * 8];
#pragma unroll
        for (int kc = 0; kc < 2; ++kc)
#pragma unroll
            for (int r = 0; r < 2; ++r)
#pragma unroll
                for (int cc = 0; cc < 4; ++cc)
                    acc[r][cc] = __builtin_amdgcn_mfma_f32_16x16x32_bf16(a[r][kc], b[cc][kc], acc[r][cc], 0, 0, 0);

        if (pf) writes(cur ^ 1);         // write late; buf cur^1's readers
                                         // drained at LAST iter's barrier
        __syncthreads();
        cur ^= 1;
    }

    if (bx < 40) {
        bf16* C  = (bx < 32) ? Q : LK;
        int ldc  = (bx < 32) ? 2048 : 512;
        const float sc = (bx < 32) ? 0.08838834764831845f * 1.4426950408889634f : 1.0f;
#pragma unroll
        for (int r = 0; r < 2; ++r)
#pragma unroll
            for (int cc = 0; cc < 4; ++cc)
#pragma unroll
                for (int i = 0; i < 4; ++i) {
                    int row = by * 128 + wm + r * 16 + q8 * 4 + i;
                    int col = n0 + cc * 16 + r16;
                    C[(size_t)row * ldc + col] = (bf16)(acc[r][cc][i] * sc);
                }
    } else {
#pragma unroll
        for (int r = 0; r < 2; ++r)
#pragma unroll
            for (int cc = 0; cc < 4; ++cc) {
                int hd = n0 + cc * 16 + r16;
                int tb = by * 128 + wm + r * 16 + q8 * 4;
                bf16x4 pk;
#pragma unroll
                for (int i = 0; i < 4; ++i) pk[i] = (bf16)acc[r][cc][i];
                *(bf16x4*)&LVt[(size_t)hd * 2048 + tb] = pk;
            }
    }
}

// ---------------------------------------------------------------------------
// out9: ATT(bf16) @ Wo(f32)^T -> fp32. A via verified gload_lds path
// (pre-swizzled source, linear dest); B reg-staged from fp32 into the same
// XOR-64 layout (T14 split). grid=(32,16), BK=64.
// ---------------------------------------------------------------------------
__global__ __launch_bounds__(256, 3) void out9(
    const bf16* __restrict__ A, const float* __restrict__ Wo, float* __restrict__ C)
{
    __shared__ __align__(16) bf16 As[2][128 * 64];
    __shared__ __align__(16) bf16 Bs[2][64 * 64];

    const int tid = threadIdx.x, lane = tid & 63, wave = tid >> 6;
    const int wm = wave * 32;
    const int r16 = lane & 15, q8 = lane >> 4;
    const int k7 = r16 & 7;
    const int m0 = blockIdx.y * 128, n0 = blockIdx.x * 64;

    const int s = tid >> 3, c = tid & 7;
    const int gqe = (c ^ (s & 7)) * 8;
    const bf16*  aSrc = A  + (size_t)(m0 + s) * 2048 + gqe;
    const float* bSrc = Wo + (size_t)(n0 + s) * 2048 + gqe;

    f32x4 acc[2][4] = {};
    float4 rb[2][2];

    auto stageA = [&](int buf, int kt) {
#pragma unroll
        for (int j = 0; j < 4; ++j)
            gload_lds16(aSrc + (size_t)j * 32 * 2048 + kt, &As[buf][(j * 256 + tid) * 8]);
    };
    auto loadB = [&](int kt) {
#pragma unroll
        for (int j = 0; j < 2; ++j) {
            const float* p = bSrc + (size_t)j * 32 * 2048 + kt;
            rb[j][0] = *(const float4*)p;
            rb[j][1] = *(const float4*)(p + 4);
        }
    };
    auto writeB = [&](int buf) {
#pragma unroll
        for (int j = 0; j < 2; ++j)
            *(bf16x8*)&Bs[buf][(j * 32 + s) * 64 + c * 8] = pack8(rb[j][0], rb[j][1]);
    };

    stageA(0, 0); loadB(0); writeB(0);
    __syncthreads();

    int cur = 0;
    for (int kt = 0; kt < 2048; kt += 64) {
        const bool pf = (kt + 64 < 2048);
        if (pf) { stageA(cur ^ 1, kt + 64); loadB(kt + 64); }

        bf16x8 a[2][2], b[4][2];
#pragma unroll
        for (int r = 0; r < 2; ++r)
#pragma unroll
            for (int kc = 0; kc < 2; ++kc)
                a[r][kc] = *(const bf16x8*)&As[cur][(wm + r * 16 + r16) * 64
                                                   + ((kc * 4 + q8) ^ k7) * 8];
#pragma unroll
        for (int cc = 0; cc < 4; ++cc)
#pragma unroll
            for (int kc = 0; kc < 2; ++kc)
                b[cc][kc] = *(const bf16x8*)&Bs[cur][(cc * 16 + r16) * 64
                                                    + ((kc * 4 + q8) ^ k7) * 8];
#pragma unroll
        for (int kc = 0; kc < 2; ++kc)
#pragma unroll
            for (int r = 0; r < 2; ++r)
#pragma unroll
                for (int cc = 0; cc < 4; ++cc)
                    acc[r][cc] = __builtin_amdgcn_mfma_f32_16x16x32_bf16(a[r][kc], b[cc][kc], acc[r][cc], 0, 0, 0);

        if (pf) writeB(cur ^ 1);
        __syncthreads();                 // drains A gloads (vmcnt) + lgkm
        cur ^= 1;
    }

#pragma unroll
    for (int r = 0; r < 2; ++r)
#pragma unroll
        for (int cc = 0; cc < 4; ++cc)
#pragma unroll
            for (int i = 0; i < 4; ++i) {
                int row = m0 + wm + r * 16 + q8 * 4 + i;
                int col = n0 + cc * 16 + r16;
                C[(size_t)row * 2048 + col] = acc[r][cc][i];
            }
}

// ---------------------------------------------------------------------------
// Attention v7 = R7-verified attn6 + 3-buffer K/V with counted vmcnt(2).
// Depth-2 prefetch: tile i+2 issued at iter i, waited at iter i+1's end --
// a full iteration (~7000 cy) of slack instead of one phase. No occupancy
// cost: 12+12+16 = 40 KB -> still 4 blocks/CU. Tail: vmcnt(0) when no
// prefetch was issued this iter. Everything else byte-identical to attn6.
// ---------------------------------------------------------------------------
__global__ __launch_bounds__(256, 4) void attn7(
    const bf16* __restrict__ Q, const bf16* __restrict__ LK,
    const bf16* __restrict__ LVt, bf16* __restrict__ O)
{
    __shared__ __align__(16) bf16 Ks[3][64 * 32];   // [s][d], chunk q^((row>>1)&3)
    __shared__ __align__(16) bf16 Vs[3][32 * 64];   // [d][s], chunk q^(row&7)
    __shared__ __align__(16) bf16 Ps[128 * 64];     // 8 regions x 16 rows x 64, XOR-swz

    const int tid  = threadIdx.x;
    const int lane = tid & 63;
    const int w    = tid >> 6;
    const int r16  = lane & 15;
    const int q8   = lane >> 4;
    const int hg = blockIdx.y, h = hg >> 2, g = hg & 3;
    const int t0 = blockIdx.x * 128;

    bf16x8 qb[2];
#pragma unroll
    for (int p = 0; p < 2; ++p)
        qb[p] = *(const bf16x8*)(Q + (size_t)(t0 + w * 32 + p * 16 + r16) * 2048
                                 + h * 128 + g * 32 + q8 * 8);

    const int kr = tid >> 2;
    const int kq = (tid & 3) ^ ((tid >> 3) & 3);
    const bf16* kg = LK + (size_t)kr * 512 + h * 32 + kq * 8;
    const int vd = tid >> 3;
    const int vq = (tid & 7) ^ ((tid >> 3) & 7);
    const bf16* vg = LVt + (size_t)(h * 32 + vd) * 2048 + vq * 8;

    const int ksw = (r16 >> 1) & 3;   // K read swizzle
    const int vsw = r16 & 7;          // V read swizzle

    const int pk7 = r16 & 7;
    const int ph  = q8 >> 1;
    const int plo = (q8 & 1) * 4;
    const int pb0 = ((w * 2 + 0) * 16 + r16) * 64;
    const int pb1 = ((w * 2 + 1) * 16 + r16) * 64;

    bf16x8 ones;
#pragma unroll
    for (int j = 0; j < 8; ++j) ones[j] = (bf16)1.0f;

    f32x4 o_acc[2][2] = {};
    f32x4 l_acc[2] = {};
    const f32x4 z = {0.f, 0.f, 0.f, 0.f};

    // prologue: tiles 0,1 into bufs 0,1 (4 loads); syncthreads drains all.
    gload_lds16(kg,                 &Ks[0][tid * 8]);
    gload_lds16(vg,                 &Vs[0][tid * 8]);
    gload_lds16(kg + (size_t)64 * 512, &Ks[1][tid * 8]);
    gload_lds16(vg + 64,               &Vs[1][tid * 8]);
    __syncthreads();

    int cur = 0, stg = 2;
    for (int sb = 0; sb < 2048; sb += 64) {
        const bool pf = (sb + 128 < 2048);
        if (pf) {
            gload_lds16(kg + (size_t)(sb + 128) * 512, &Ks[stg][tid * 8]);
            gload_lds16(vg + (sb + 128),               &Vs[stg][tid * 8]);
        }
        const bf16* ks = Ks[cur];
        const bf16* vs = Vs[cur];

        bf16x8 kb[4], vb[2][2];
#pragma unroll
        for (int cc = 0; cc < 4; ++cc)
            kb[cc] = *(const bf16x8*)&ks[(cc * 16 + r16) * 32 + (q8 ^ ksw) * 8];
#pragma unroll
        for (int kk = 0; kk < 2; ++kk)
#pragma unroll
            for (int ct = 0; ct < 2; ++ct)
                vb[kk][ct] = *(const bf16x8*)&vs[(ct * 16 + r16) * 64
                                                 + (((kk * 4 + q8) ^ vsw) * 8)];

        // ---- phase A: QK^T + exp + P-write for both strips ----
#pragma unroll
        for (int p = 0; p < 2; ++p) {
            const int pbase = p ? pb1 : pb0;
            f32x4 sv[4];
            __builtin_amdgcn_s_setprio(1);
#pragma unroll
            for (int cc = 0; cc < 4; ++cc)
                sv[cc] = __builtin_amdgcn_mfma_f32_16x16x32_bf16(kb[cc], qb[p], z, 0, 0, 0);
            __builtin_amdgcn_s_setprio(0);
#pragma unroll
            for (int cc = 0; cc < 4; ++cc) {
                bf16x4 pkv;
#pragma unroll
                for (int i = 0; i < 4; ++i) pkv[i] = (bf16)exp2f(sv[cc][i]);
                *(bf16x4*)&Ps[pbase + ((cc * 2 + ph) ^ pk7) * 8 + plo] = pkv;
            }
        }

        // ---- phase B: PV + row-sum MFMAs for both strips ----
        __builtin_amdgcn_s_setprio(1);
#pragma unroll
        for (int p = 0; p < 2; ++p) {
            const int pbase = p ? pb1 : pb0;
#pragma unroll
            for (int kk = 0; kk < 2; ++kk) {
                bf16x8 ap = *(const bf16x8*)&Ps[pbase + ((kk * 4 + q8) ^ pk7) * 8];
#pragma unroll
                for (int ct = 0; ct < 2; ++ct)
                    o_acc[p][ct] = __builtin_amdgcn_mfma_f32_16x16x32_bf16(ap, vb[kk][ct], o_acc[p][ct], 0, 0, 0);
                l_acc[p] = __builtin_amdgcn_mfma_f32_16x16x32_bf16(ap, ones, l_acc[p], 0, 0, 0);
            }
        }
        __builtin_amdgcn_s_setprio(0);

        // counted wait: tile i+1's 2 loads retired (oldest), tile i+2's 2 may
        // stay in flight. Tail (no prefetch): full drain.
        if (pf) asm volatile("s_waitcnt vmcnt(2) lgkmcnt(0)" ::: "memory");
        else    asm volatile("s_waitcnt vmcnt(0) lgkmcnt(0)" ::: "memory");
        __builtin_amdgcn_s_barrier();
        __builtin_amdgcn_sched_barrier(0);
        cur = (cur == 2) ? 0 : cur + 1;
        stg = (stg == 2) ? 0 : stg + 1;
    }

    // epilogue: l_acc[p][i] IS the row-sum for t_local = q8*4+i
#pragma unroll
    for (int p = 0; p < 2; ++p)
#pragma unroll
        for (int i = 0; i < 4; ++i) {
            float inv = 1.0f / l_acc[p][i];
            int t = t0 + w * 32 + p * 16 + q8 * 4 + i;
#pragma unroll
            for (int ct = 0; ct < 2; ++ct) {
                int d = ct * 16 + r16;
                O[(size_t)t * 2048 + h * 128 + g * 32 + d] = (bf16)(o_acc[p][ct][i] * inv);
            }
        }
}

// ---------------------------------------------------------------------------
// Contract: inputs fp32, output fp32. cvt5 eliminated: proj9/out9 stage
// straight from fp32 (identical (bf16) rounding -> bit-identical results).
// ws need: (4M + 1M + 1M) bf16 = 12 MB (ws >= 24 MB observed in all runs).
// ---------------------------------------------------------------------------
extern "C" void kernel_launch(void* const* d_in, const int* in_sizes, int n_in,
                              void* d_out, int out_size, void* d_ws, size_t ws_size,
                              hipStream_t stream) {
    const float* x   = (const float*)d_in[0];
    const float* Wq  = (const float*)d_in[1];
    // d_in[2]=Wk, d_in[3]=Wv: computed-but-unused in the reference -> skipped
    const float* Wlk = (const float*)d_in[4];
    const float* Wlv = (const float*)d_in[5];
    const float* Wo  = (const float*)d_in[6];
    float* out = (float*)d_out;

    const size_t M4 = 4194304, M1 = 1048576;
    bf16* Qp  = (bf16*)d_ws;
    bf16* LKp = Qp + M4;
    bf16* LVt = LKp + M1;
    bf16* ATT = Qp;                 // alias: each attn block reads its own Q
                                    // cells (prologue) before writing them

    proj9<<<dim3(48, 16), 256, 0, stream>>>(x, Wq, Wlk, Wlv, Qp, LKp, LVt);
    attn7<<<dim3(16, 64), 256, 0, stream>>>(Qp, LKp, LVt, ATT);
    out9<<<dim3(32, 16), 256, 0, stream>>>(ATT, Wo, out);
}

// Round 11
// 265.956 us; speedup vs baseline: 1.1083x; 1.1083x over previous
//
#include <hip/hip_runtime.h>
#include <hip/hip_bf16.h>

typedef __bf16 bf16;
typedef __bf16 bf16x4 __attribute__((ext_vector_type(4)));
typedef __bf16 bf16x8 __attribute__((ext_vector_type(8)));
typedef float  f32x4  __attribute__((ext_vector_type(4)));

#define AS1 __attribute__((address_space(1)))
#define AS3 __attribute__((address_space(3)))

__device__ __forceinline__ void gload_lds16(const bf16* g, bf16* l) {
    __builtin_amdgcn_global_load_lds((const AS1 void*)g, (AS3 void*)l, 16, 0, 0);
}

__device__ __forceinline__ void stage8_f32(const float* s, bf16* l) {
    float4 a = *(const float4*)s;
    float4 b = *(const float4*)(s + 4);
    bf16x8 o;
    o[0] = (bf16)a.x; o[1] = (bf16)a.y; o[2] = (bf16)a.z; o[3] = (bf16)a.w;
    o[4] = (bf16)b.x; o[5] = (bf16)b.y; o[6] = (bf16)b.z; o[7] = (bf16)b.w;
    *(bf16x8*)l = o;
}

// ---------------------------------------------------------------------------
// 128x64 GEMM tile core, BK=64, bf16, gload_lds staging (R8-VERIFIED: this
// exact core measured total 267.0 us; R10's reg-staging variant regressed
// +47 us, reproducing m151: global_load_lds > reg-staging at linear tiles).
// XOR-64 swizzle both-sides (rule #21): linear LDS dest + pre-swizzled
// global source + swizzled read. Read bank: ((kc*4+q8)^(r16&7)) -> 8/bank.
// ---------------------------------------------------------------------------
__device__ __forceinline__ void gemm_core64_k64(
    const bf16* __restrict__ A, const bf16* __restrict__ B,
    int m0, int n0, int K, f32x4 (&acc)[2][4],
    int wm, int r16, int q8)
{
    __shared__ __align__(16) bf16 As[2][128 * 64];  // 16 KB each
    __shared__ __align__(16) bf16 Bs[2][64 * 64];   //  8 KB each

    const int tid  = threadIdx.x;
    const int arow = tid >> 3;                              // 0..31
    const int acol = ((tid & 7) ^ ((tid >> 3) & 7)) * 8;    // inverse-swz src col
    const int k7   = r16 & 7;                               // read swizzle key

    auto stage = [&](int buf, int kt) {
#pragma unroll
        for (int j = 0; j < 4; ++j)
            gload_lds16(A + (size_t)(m0 + j * 32 + arow) * K + kt + acol,
                        &As[buf][(j * 256 + tid) * 8]);
#pragma unroll
        for (int j = 0; j < 2; ++j)
            gload_lds16(B + (size_t)(n0 + j * 32 + arow) * K + kt + acol,
                        &Bs[buf][(j * 256 + tid) * 8]);
    };

    stage(0, 0);
    __syncthreads();

    int cur = 0;
    for (int kt = 0; kt < K; kt += 64) {
        if (kt + 64 < K) stage(cur ^ 1, kt + 64);

        bf16x8 a[2][2], b[4][2];
#pragma unroll
        for (int r = 0; r < 2; ++r)
#pragma unroll
            for (int kc = 0; kc < 2; ++kc)
                a[r][kc] = *(const bf16x8*)&As[cur][(wm + r * 16 + r16) * 64
                                                   + ((kc * 4 + q8) ^ k7) * 8];
#pragma unroll
        for (int c = 0; c < 4; ++c)
#pragma unroll
            for (int kc = 0; kc < 2; ++kc)
                b[c][kc] = *(const bf16x8*)&Bs[cur][(c * 16 + r16) * 64
                                                   + ((kc * 4 + q8) ^ k7) * 8];
#pragma unroll
        for (int kc = 0; kc < 2; ++kc)
#pragma unroll
            for (int r = 0; r < 2; ++r)
#pragma unroll
                for (int c = 0; c < 4; ++c)
                    acc[r][c] = __builtin_amdgcn_mfma_f32_16x16x32_bf16(a[r][kc], b[c][kc], acc[r][c], 0, 0, 0);

        // publish buf[cur^1]: prefetch landed (vmcnt), reads of buf[cur]
        // drained (lgkm) -> safe to overwrite buf[cur] next iter.
        asm volatile("s_waitcnt vmcnt(0) lgkmcnt(0)" ::: "memory");
        __builtin_amdgcn_s_barrier();
        __builtin_amdgcn_sched_barrier(0);
        cur ^= 1;
    }
}

// fp32 -> bf16 bulk convert: y selects {x, Wq, Wlk, Wlv}. (Wo's conversion
// moved into attn7's epilogue -- rides attn's idle HBM bandwidth.)
__global__ __launch_bounds__(256) void cvt4(
    const float* __restrict__ s0, const float* __restrict__ s1,
    const float* __restrict__ s2, const float* __restrict__ s3,
    bf16* __restrict__ d0, bf16* __restrict__ d1, bf16* __restrict__ d2,
    bf16* __restrict__ d3)
{
    const float* S[4] = {s0, s1, s2, s3};
    bf16*        D[4] = {d0, d1, d2, d3};
    const int    N[4] = {4194304, 4194304, 1048576, 1048576};
    int y = blockIdx.y;
    int base = (blockIdx.x * 256 + threadIdx.x) * 8;
    if (base >= N[y]) return;
    stage8_f32(S[y] + base, D[y] + base);
}

// ---------------------------------------------------------------------------
// Projections (R8-verified fast path): grid=(48,16), 64-wide N tiles;
// bx<32 -> Q (PRE-SCALED by 1/sqrt(128)*log2e), 32..39 -> LK,
// 40..47 -> LV stored TRANSPOSED as LVt[hd=512][T=2048].
// ---------------------------------------------------------------------------
__global__ __launch_bounds__(256) void proj_k64(
    const bf16* __restrict__ x, const bf16* __restrict__ Wq,
    const bf16* __restrict__ Wlk, const bf16* __restrict__ Wlv,
    bf16* __restrict__ Q, bf16* __restrict__ LK, bf16* __restrict__ LVt)
{
    const int bx = blockIdx.x, by = blockIdx.y;
    const int tid = threadIdx.x, lane = tid & 63, wave = tid >> 6;
    const int wm = wave * 32;
    const int r16 = lane & 15, q8 = lane >> 4;
    f32x4 acc[2][4] = {};

    const bf16* Bv; int n0;
    if (bx < 32)      { Bv = Wq;  n0 = bx * 64; }
    else if (bx < 40) { Bv = Wlk; n0 = (bx - 32) * 64; }
    else              { Bv = Wlv; n0 = (bx - 40) * 64; }

    gemm_core64_k64(x, Bv, by * 128, n0, 2048, acc, wm, r16, q8);

    if (bx < 40) {
        bf16* C  = (bx < 32) ? Q : LK;
        int ldc  = (bx < 32) ? 2048 : 512;
        const float sc = (bx < 32) ? 0.08838834764831845f * 1.4426950408889634f : 1.0f;
#pragma unroll
        for (int r = 0; r < 2; ++r)
#pragma unroll
            for (int c = 0; c < 4; ++c)
#pragma unroll
                for (int i = 0; i < 4; ++i) {
                    int row = by * 128 + wm + r * 16 + q8 * 4 + i;
                    int col = n0 + c * 16 + r16;
                    C[(size_t)row * ldc + col] = (bf16)(acc[r][c][i] * sc);
                }
    } else {
#pragma unroll
        for (int r = 0; r < 2; ++r)
#pragma unroll
            for (int c = 0; c < 4; ++c) {
                int hd = n0 + c * 16 + r16;
                int tb = by * 128 + wm + r * 16 + q8 * 4;
                bf16x4 pk;
#pragma unroll
                for (int i = 0; i < 4; ++i) pk[i] = (bf16)acc[r][c][i];
                *(bf16x4*)&LVt[(size_t)hd * 2048 + tb] = pk;
            }
    }
}

// Output GEMM (R8-verified fast path): out = ATT(bf16) @ Wob(bf16)^T -> fp32.
// grid=(32,16), 64-wide tiles.
__global__ __launch_bounds__(256) void out_k64(
    const bf16* __restrict__ A, const bf16* __restrict__ Wob, float* __restrict__ C)
{
    const int tid = threadIdx.x, lane = tid & 63, wave = tid >> 6;
    const int wm = wave * 32;
    const int r16 = lane & 15, q8 = lane >> 4;
    f32x4 acc[2][4] = {};
    gemm_core64_k64(A, Wob, blockIdx.y * 128, blockIdx.x * 64, 2048, acc, wm, r16, q8);
#pragma unroll
    for (int r = 0; r < 2; ++r)
#pragma unroll
        for (int c = 0; c < 4; ++c)
#pragma unroll
            for (int i = 0; i < 4; ++i) {
                int row = blockIdx.y * 128 + wm + r * 16 + q8 * 4 + i;
                int col = blockIdx.x * 64 + c * 16 + r16;
                C[(size_t)row * 2048 + col] = acc[r][c][i];
            }
}

// ---------------------------------------------------------------------------
// Attention v7 (R10-verified: 91.5 us, passed) + Wo fp32->bf16 conversion in
// the epilogue (1024 blk x 256 thr x 8 el x 2 it == 4194304 == |Wo| exactly;
// attn runs at 4% HBM so the 25 MB rides free bandwidth).
// ---------------------------------------------------------------------------
__global__ __launch_bounds__(256, 4) void attn7(
    const bf16* __restrict__ Q, const bf16* __restrict__ LK,
    const bf16* __restrict__ LVt, bf16* __restrict__ O,
    const float* __restrict__ Wo, bf16* __restrict__ Wob)
{
    __shared__ __align__(16) bf16 Ks[3][64 * 32];   // [s][d], chunk q^((row>>1)&3)
    __shared__ __align__(16) bf16 Vs[3][32 * 64];   // [d][s], chunk q^(row&7)
    __shared__ __align__(16) bf16 Ps[128 * 64];     // 8 regions x 16 rows x 64, XOR-swz

    const int tid  = threadIdx.x;
    const int lane = tid & 63;
    const int w    = tid >> 6;
    const int r16  = lane & 15;
    const int q8   = lane >> 4;
    const int hg = blockIdx.y, h = hg >> 2, g = hg & 3;
    const int t0 = blockIdx.x * 128;

    bf16x8 qb[2];
#pragma unroll
    for (int p = 0; p < 2; ++p)
        qb[p] = *(const bf16x8*)(Q + (size_t)(t0 + w * 32 + p * 16 + r16) * 2048
                                 + h * 128 + g * 32 + q8 * 8);

    const int kr = tid >> 2;
    const int kq = (tid & 3) ^ ((tid >> 3) & 3);
    const bf16* kg = LK + (size_t)kr * 512 + h * 32 + kq * 8;
    const int vd = tid >> 3;
    const int vq = (tid & 7) ^ ((tid >> 3) & 7);
    const bf16* vg = LVt + (size_t)(h * 32 + vd) * 2048 + vq * 8;

    const int ksw = (r16 >> 1) & 3;   // K read swizzle
    const int vsw = r16 & 7;          // V read swizzle

    const int pk7 = r16 & 7;
    const int ph  = q8 >> 1;
    const int plo = (q8 & 1) * 4;
    const int pb0 = ((w * 2 + 0) * 16 + r16) * 64;
    const int pb1 = ((w * 2 + 1) * 16 + r16) * 64;

    bf16x8 ones;
#pragma unroll
    for (int j = 0; j < 8; ++j) ones[j] = (bf16)1.0f;

    f32x4 o_acc[2][2] = {};
    f32x4 l_acc[2] = {};
    const f32x4 z = {0.f, 0.f, 0.f, 0.f};

    // prologue: tiles 0,1 into bufs 0,1; syncthreads drains all.
    gload_lds16(kg,                 &Ks[0][tid * 8]);
    gload_lds16(vg,                 &Vs[0][tid * 8]);
    gload_lds16(kg + (size_t)64 * 512, &Ks[1][tid * 8]);
    gload_lds16(vg + 64,               &Vs[1][tid * 8]);
    __syncthreads();

    int cur = 0, stg = 2;
    for (int sb = 0; sb < 2048; sb += 64) {
        const bool pf = (sb + 128 < 2048);
        if (pf) {
            gload_lds16(kg + (size_t)(sb + 128) * 512, &Ks[stg][tid * 8]);
            gload_lds16(vg + (sb + 128),               &Vs[stg][tid * 8]);
        }
        const bf16* ks = Ks[cur];
        const bf16* vs = Vs[cur];

        bf16x8 kb[4], vb[2][2];
#pragma unroll
        for (int cc = 0; cc < 4; ++cc)
            kb[cc] = *(const bf16x8*)&ks[(cc * 16 + r16) * 32 + (q8 ^ ksw) * 8];
#pragma unroll
        for (int kk = 0; kk < 2; ++kk)
#pragma unroll
            for (int ct = 0; ct < 2; ++ct)
                vb[kk][ct] = *(const bf16x8*)&vs[(ct * 16 + r16) * 64
                                                 + (((kk * 4 + q8) ^ vsw) * 8)];

        // ---- phase A: QK^T + exp + P-write for both strips ----
#pragma unroll
        for (int p = 0; p < 2; ++p) {
            const int pbase = p ? pb1 : pb0;
            f32x4 sv[4];
            __builtin_amdgcn_s_setprio(1);
#pragma unroll
            for (int cc = 0; cc < 4; ++cc)
                sv[cc] = __builtin_amdgcn_mfma_f32_16x16x32_bf16(kb[cc], qb[p], z, 0, 0, 0);
            __builtin_amdgcn_s_setprio(0);
#pragma unroll
            for (int cc = 0; cc < 4; ++cc) {
                bf16x4 pkv;
#pragma unroll
                for (int i = 0; i < 4; ++i) pkv[i] = (bf16)exp2f(sv[cc][i]);
                *(bf16x4*)&Ps[pbase + ((cc * 2 + ph) ^ pk7) * 8 + plo] = pkv;
            }
        }

        // ---- phase B: PV + row-sum MFMAs for both strips ----
        __builtin_amdgcn_s_setprio(1);
#pragma unroll
        for (int p = 0; p < 2; ++p) {
            const int pbase = p ? pb1 : pb0;
#pragma unroll
            for (int kk = 0; kk < 2; ++kk) {
                bf16x8 ap = *(const bf16x8*)&Ps[pbase + ((kk * 4 + q8) ^ pk7) * 8];
#pragma unroll
                for (int ct = 0; ct < 2; ++ct)
                    o_acc[p][ct] = __builtin_amdgcn_mfma_f32_16x16x32_bf16(ap, vb[kk][ct], o_acc[p][ct], 0, 0, 0);
                l_acc[p] = __builtin_amdgcn_mfma_f32_16x16x32_bf16(ap, ones, l_acc[p], 0, 0, 0);
            }
        }
        __builtin_amdgcn_s_setprio(0);

        // counted wait: tile i+1's loads retired, tile i+2's may stay in
        // flight. Tail (no prefetch): full drain.
        if (pf) asm volatile("s_waitcnt vmcnt(2) lgkmcnt(0)" ::: "memory");
        else    asm volatile("s_waitcnt vmcnt(0) lgkmcnt(0)" ::: "memory");
        __builtin_amdgcn_s_barrier();
        __builtin_amdgcn_sched_barrier(0);
        cur = (cur == 2) ? 0 : cur + 1;
        stg = (stg == 2) ? 0 : stg + 1;
    }

    // epilogue: l_acc[p][i] IS the row-sum for t_local = q8*4+i
#pragma unroll
    for (int p = 0; p < 2; ++p)
#pragma unroll
        for (int i = 0; i < 4; ++i) {
            float inv = 1.0f / l_acc[p][i];
            int t = t0 + w * 32 + p * 16 + q8 * 4 + i;
#pragma unroll
            for (int ct = 0; ct < 2; ++ct) {
                int d = ct * 16 + r16;
                O[(size_t)t * 2048 + h * 128 + g * 32 + d] = (bf16)(o_acc[p][ct][i] * inv);
            }
        }

    // folded Wo conversion: each block converts its exact 4096-elem slice.
    {
        const int bid = blockIdx.y * 16 + blockIdx.x;   // gridDim.x == 16
#pragma unroll
        for (int it = 0; it < 2; ++it) {
            size_t off = (size_t)bid * 4096 + (size_t)it * 2048 + (size_t)tid * 8;
            stage8_f32(Wo + off, Wob + off);
        }
    }
}

// ---------------------------------------------------------------------------
// Contract: inputs fp32, output fp32. d_out doubles as scratch for xb/Wqb
// (dead before out_k64 writes). ws layout (24 MB, satisfied in all runs):
// Wlkb(1M) Wlvb(1M) Wob(4M) Qp(4M) LKp(1M) LVt(1M) bf16 elems.
// ---------------------------------------------------------------------------
extern "C" void kernel_launch(void* const* d_in, const int* in_sizes, int n_in,
                              void* d_out, int out_size, void* d_ws, size_t ws_size,
                              hipStream_t stream) {
    const float* x   = (const float*)d_in[0];
    const float* Wq  = (const float*)d_in[1];
    // d_in[2]=Wk, d_in[3]=Wv: computed-but-unused in the reference -> skipped
    const float* Wlk = (const float*)d_in[4];
    const float* Wlv = (const float*)d_in[5];
    const float* Wo  = (const float*)d_in[6];
    float* out = (float*)d_out;

    const size_t M4 = 4194304, M1 = 1048576;
    bf16* xb   = (bf16*)d_out;      // d_out scratch: dead before out_k64 writes
    bf16* Wqb  = xb + M4;
    bf16* p    = (bf16*)d_ws;
    bf16* Wlkb = p; p += M1;
    bf16* Wlvb = p; p += M1;
    bf16* Wob  = p; p += M4;
    bf16* Qp   = p; p += M4;
    bf16* LKp  = p; p += M1;
    bf16* LVt  = p;
    bf16* ATT  = Qp;                // alias: attn blocks read their own Q cells first

    cvt4<<<dim3(2048, 4), 256, 0, stream>>>(x, Wq, Wlk, Wlv,
                                            xb, Wqb, Wlkb, Wlvb);
    proj_k64<<<dim3(48, 16), 256, 0, stream>>>(xb, Wqb, Wlkb, Wlvb,
                                               Qp, LKp, LVt);
    attn7<<<dim3(16, 64), 256, 0, stream>>>(Qp, LKp, LVt, ATT, Wo, Wob);
    out_k64<<<dim3(32, 16), 256, 0, stream>>>(ATT, Wob, out);
}

// Round 13
// 263.003 us; speedup vs baseline: 1.1208x; 1.0112x over previous
//
#include <hip/hip_runtime.h>
#include <hip/hip_bf16.h>

typedef __bf16 bf16;
typedef __bf16 bf16x4 __attribute__((ext_vector_type(4)));
typedef __bf16 bf16x8 __attribute__((ext_vector_type(8)));
typedef float  f32x4  __attribute__((ext_vector_type(4)));

#define AS1 __attribute__((address_space(1)))
#define AS3 __attribute__((address_space(3)))

__device__ __forceinline__ void gload_lds16(const bf16* g, bf16* l) {
    __builtin_amdgcn_global_load_lds((const AS1 void*)g, (AS3 void*)l, 16, 0, 0);
}

__device__ __forceinline__ void stage8_f32(const float* s, bf16* l) {
    float4 a = *(const float4*)s;
    float4 b = *(const float4*)(s + 4);
    bf16x8 o;
    o[0] = (bf16)a.x; o[1] = (bf16)a.y; o[2] = (bf16)a.z; o[3] = (bf16)a.w;
    o[4] = (bf16)b.x; o[5] = (bf16)b.y; o[6] = (bf16)b.z; o[7] = (bf16)b.w;
    *(bf16x8*)l = o;
}

// ---------------------------------------------------------------------------
// 128x64 GEMM tile core, BK=64, bf16, gload_lds staging (R8/R11-VERIFIED).
// XOR-64 swizzle both-sides (rule #21): linear LDS dest + pre-swizzled
// global source + swizzled read. Read bank: ((kc*4+q8)^(r16&7)) -> 8/bank.
// ---------------------------------------------------------------------------
__device__ __forceinline__ void gemm_core64_k64(
    const bf16* __restrict__ A, const bf16* __restrict__ B,
    int m0, int n0, int K, f32x4 (&acc)[2][4],
    int wm, int r16, int q8)
{
    __shared__ __align__(16) bf16 As[2][128 * 64];  // 16 KB each
    __shared__ __align__(16) bf16 Bs[2][64 * 64];   //  8 KB each

    const int tid  = threadIdx.x;
    const int arow = tid >> 3;                              // 0..31
    const int acol = ((tid & 7) ^ ((tid >> 3) & 7)) * 8;    // inverse-swz src col
    const int k7   = r16 & 7;                               // read swizzle key

    auto stage = [&](int buf, int kt) {
#pragma unroll
        for (int j = 0; j < 4; ++j)
            gload_lds16(A + (size_t)(m0 + j * 32 + arow) * K + kt + acol,
                        &As[buf][(j * 256 + tid) * 8]);
#pragma unroll
        for (int j = 0; j < 2; ++j)
            gload_lds16(B + (size_t)(n0 + j * 32 + arow) * K + kt + acol,
                        &Bs[buf][(j * 256 + tid) * 8]);
    };

    stage(0, 0);
    __syncthreads();

    int cur = 0;
    for (int kt = 0; kt < K; kt += 64) {
        if (kt + 64 < K) stage(cur ^ 1, kt + 64);

        bf16x8 a[2][2], b[4][2];
#pragma unroll
        for (int r = 0; r < 2; ++r)
#pragma unroll
            for (int kc = 0; kc < 2; ++kc)
                a[r][kc] = *(const bf16x8*)&As[cur][(wm + r * 16 + r16) * 64
                                                   + ((kc * 4 + q8) ^ k7) * 8];
#pragma unroll
        for (int c = 0; c < 4; ++c)
#pragma unroll
            for (int kc = 0; kc < 2; ++kc)
                b[c][kc] = *(const bf16x8*)&Bs[cur][(c * 16 + r16) * 64
                                                   + ((kc * 4 + q8) ^ k7) * 8];
#pragma unroll
        for (int kc = 0; kc < 2; ++kc)
#pragma unroll
            for (int r = 0; r < 2; ++r)
#pragma unroll
                for (int c = 0; c < 4; ++c)
                    acc[r][c] = __builtin_amdgcn_mfma_f32_16x16x32_bf16(a[r][kc], b[c][kc], acc[r][c], 0, 0, 0);

        // publish buf[cur^1]: prefetch landed (vmcnt), reads of buf[cur]
        // drained (lgkm) -> safe to overwrite buf[cur] next iter.
        asm volatile("s_waitcnt vmcnt(0) lgkmcnt(0)" ::: "memory");
        __builtin_amdgcn_s_barrier();
        __builtin_amdgcn_sched_barrier(0);
        cur ^= 1;
    }
}

// fp32 -> bf16 bulk convert, compact 1D grid (5120 blocks, no no-op blocks):
// [0,2048)->x, [2048,4096)->Wq, [4096,4608)->Wlk, [4608,5120)->Wlv.
__global__ __launch_bounds__(256) void cvt4c(
    const float* __restrict__ s0, const float* __restrict__ s1,
    const float* __restrict__ s2, const float* __restrict__ s3,
    bf16* __restrict__ d0, bf16* __restrict__ d1, bf16* __restrict__ d2,
    bf16* __restrict__ d3)
{
    int bid = blockIdx.x;
    const float* S; bf16* D; int cb;
    if (bid < 2048)      { S = s0; D = d0; cb = bid; }
    else if (bid < 4096) { S = s1; D = d1; cb = bid - 2048; }
    else if (bid < 4608) { S = s2; D = d2; cb = bid - 4096; }
    else                 { S = s3; D = d3; cb = bid - 4608; }
    int off = (cb * 256 + threadIdx.x) * 8;
    stage8_f32(S + off, D + off);
}

// ---------------------------------------------------------------------------
// Projections: logical grid 48x16 (64-wide N tiles), XCD-rectangle swizzle
// (T1): dispatch id hw -> XCD hw&7; each XCD owns a 12bx x 8by rectangle
// (B-set 3MB + A-set 4MB ~ L2-resident), ordered by-fastest so the B-panel
// (256 KB) stays hot. 768%8==0 -> bijective. bx<32 -> Q (PRE-SCALED by
// 1/sqrt(128)*log2e), 32..39 -> LK, 40..47 -> LVt[hd=512][T=2048].
// ---------------------------------------------------------------------------
__global__ __launch_bounds__(256) void proj_k64(
    const bf16* __restrict__ x, const bf16* __restrict__ Wq,
    const bf16* __restrict__ Wlk, const bf16* __restrict__ Wlv,
    bf16* __restrict__ Q, bf16* __restrict__ LK, bf16* __restrict__ LVt)
{
    const int hw  = blockIdx.x + 48 * blockIdx.y;   // dispatch-linear
    const int xcd = hw & 7, c = hw >> 3;            // c in [0,96)
    const int bx  = (xcd & 3) * 12 + c / 8;         // lbx = c/8 in [0,12)
    const int by  = (xcd >> 2) * 8 + (c & 7);       // lby = c%8, fastest

    const int tid = threadIdx.x, lane = tid & 63, wave = tid >> 6;
    const int wm = wave * 32;
    const int r16 = lane & 15, q8 = lane >> 4;
    f32x4 acc[2][4] = {};

    const bf16* Bv; int n0;
    if (bx < 32)      { Bv = Wq;  n0 = bx * 64; }
    else if (bx < 40) { Bv = Wlk; n0 = (bx - 32) * 64; }
    else              { Bv = Wlv; n0 = (bx - 40) * 64; }

    gemm_core64_k64(x, Bv, by * 128, n0, 2048, acc, wm, r16, q8);

    if (bx < 40) {
        bf16* C  = (bx < 32) ? Q : LK;
        int ldc  = (bx < 32) ? 2048 : 512;
        const float sc = (bx < 32) ? 0.08838834764831845f * 1.4426950408889634f : 1.0f;
#pragma unroll
        for (int r = 0; r < 2; ++r)
#pragma unroll
            for (int cc = 0; cc < 4; ++cc)
#pragma unroll
                for (int i = 0; i < 4; ++i) {
                    int row = by * 128 + wm + r * 16 + q8 * 4 + i;
                    int col = n0 + cc * 16 + r16;
                    C[(size_t)row * ldc + col] = (bf16)(acc[r][cc][i] * sc);
                }
    } else {
#pragma unroll
        for (int r = 0; r < 2; ++r)
#pragma unroll
            for (int cc = 0; cc < 4; ++cc) {
                int hd = n0 + cc * 16 + r16;
                int tb = by * 128 + wm + r * 16 + q8 * 4;
                bf16x4 pk;
#pragma unroll
                for (int i = 0; i < 4; ++i) pk[i] = (bf16)acc[r][cc][i];
                *(bf16x4*)&LVt[(size_t)hd * 2048 + tb] = pk;
            }
    }
}

// Output GEMM: out = ATT(bf16) @ Wob(bf16)^T -> fp32. Logical grid 32x16,
// XCD-rectangle swizzle: each XCD owns 8bx x 8by (2MB B + 4MB A). 512%8==0.
__global__ __launch_bounds__(256) void out_k64(
    const bf16* __restrict__ A, const bf16* __restrict__ Wob, float* __restrict__ C)
{
    const int hw  = blockIdx.x + 32 * blockIdx.y;
    const int xcd = hw & 7, c = hw >> 3;            // c in [0,64)
    const int bx  = (xcd & 3) * 8 + c / 8;          // lbx = c/8 in [0,8)
    const int by  = (xcd >> 2) * 8 + (c & 7);       // lby = c%8, fastest

    const int tid = threadIdx.x, lane = tid & 63, wave = tid >> 6;
    const int wm = wave * 32;
    const int r16 = lane & 15, q8 = lane >> 4;
    f32x4 acc[2][4] = {};
    gemm_core64_k64(A, Wob, by * 128, bx * 64, 2048, acc, wm, r16, q8);
#pragma unroll
    for (int r = 0; r < 2; ++r)
#pragma unroll
        for (int cc = 0; cc < 4; ++cc)
#pragma unroll
            for (int i = 0; i < 4; ++i) {
                int row = by * 128 + wm + r * 16 + q8 * 4 + i;
                int col = bx * 64 + cc * 16 + r16;
                C[(size_t)row * 2048 + col] = acc[r][cc][i];
            }
}

// ---------------------------------------------------------------------------
// Attention v7 -- FROZEN (R11-verified: 93.0 us with the folded Wo cvt).
// 3-buffer K/V, counted vmcnt(2); phase-split QK/exp vs PV; ones-MFMA lsum;
// conflict-free XOR Ps. Epilogue converts this block's exact Wo slice.
// ---------------------------------------------------------------------------
__global__ __launch_bounds__(256, 4) void attn7(
    const bf16* __restrict__ Q, const bf16* __restrict__ LK,
    const bf16* __restrict__ LVt, bf16* __restrict__ O,
    const float* __restrict__ Wo, bf16* __restrict__ Wob)
{
    __shared__ __align__(16) bf16 Ks[3][64 * 32];   // [s][d], chunk q^((row>>1)&3)
    __shared__ __align__(16) bf16 Vs[3][32 * 64];   // [d][s], chunk q^(row&7)
    __shared__ __align__(16) bf16 Ps[128 * 64];     // 8 regions x 16 rows x 64, XOR-swz

    const int tid  = threadIdx.x;
    const int lane = tid & 63;
    const int w    = tid >> 6;
    const int r16  = lane & 15;
    const int q8   = lane >> 4;
    const int hg = blockIdx.y, h = hg >> 2, g = hg & 3;
    const int t0 = blockIdx.x * 128;

    bf16x8 qb[2];
#pragma unroll
    for (int p = 0; p < 2; ++p)
        qb[p] = *(const bf16x8*)(Q + (size_t)(t0 + w * 32 + p * 16 + r16) * 2048
                                 + h * 128 + g * 32 + q8 * 8);

    const int kr = tid >> 2;
    const int kq = (tid & 3) ^ ((tid >> 3) & 3);
    const bf16* kg = LK + (size_t)kr * 512 + h * 32 + kq * 8;
    const int vd = tid >> 3;
    const int vq = (tid & 7) ^ ((tid >> 3) & 7);
    const bf16* vg = LVt + (size_t)(h * 32 + vd) * 2048 + vq * 8;

    const int ksw = (r16 >> 1) & 3;   // K read swizzle
    const int vsw = r16 & 7;          // V read swizzle

    const int pk7 = r16 & 7;
    const int ph  = q8 >> 1;
    const int plo = (q8 & 1) * 4;
    const int pb0 = ((w * 2 + 0) * 16 + r16) * 64;
    const int pb1 = ((w * 2 + 1) * 16 + r16) * 64;

    bf16x8 ones;
#pragma unroll
    for (int j = 0; j < 8; ++j) ones[j] = (bf16)1.0f;

    f32x4 o_acc[2][2] = {};
    f32x4 l_acc[2] = {};
    const f32x4 z = {0.f, 0.f, 0.f, 0.f};

    // prologue: tiles 0,1 into bufs 0,1; syncthreads drains all.
    gload_lds16(kg,                 &Ks[0][tid * 8]);
    gload_lds16(vg,                 &Vs[0][tid * 8]);
    gload_lds16(kg + (size_t)64 * 512, &Ks[1][tid * 8]);
    gload_lds16(vg + 64,               &Vs[1][tid * 8]);
    __syncthreads();

    int cur = 0, stg = 2;
    for (int sb = 0; sb < 2048; sb += 64) {
        const bool pf = (sb + 128 < 2048);
        if (pf) {
            gload_lds16(kg + (size_t)(sb + 128) * 512, &Ks[stg][tid * 8]);
            gload_lds16(vg + (sb + 128),               &Vs[stg][tid * 8]);
        }
        const bf16* ks = Ks[cur];
        const bf16* vs = Vs[cur];

        bf16x8 kb[4], vb[2][2];
#pragma unroll
        for (int cc = 0; cc < 4; ++cc)
            kb[cc] = *(const bf16x8*)&ks[(cc * 16 + r16) * 32 + (q8 ^ ksw) * 8];
#pragma unroll
        for (int kk = 0; kk < 2; ++kk)
#pragma unroll
            for (int ct = 0; ct < 2; ++ct)
                vb[kk][ct] = *(const bf16x8*)&vs[(ct * 16 + r16) * 64
                                                 + (((kk * 4 + q8) ^ vsw) * 8)];

        // ---- phase A: QK^T + exp + P-write for both strips ----
#pragma unroll
        for (int p = 0; p < 2; ++p) {
            const int pbase = p ? pb1 : pb0;
            f32x4 sv[4];
            __builtin_amdgcn_s_setprio(1);
#pragma unroll
            for (int cc = 0; cc < 4; ++cc)
                sv[cc] = __builtin_amdgcn_mfma_f32_16x16x32_bf16(kb[cc], qb[p], z, 0, 0, 0);
            __builtin_amdgcn_s_setprio(0);
#pragma unroll
            for (int cc = 0; cc < 4; ++cc) {
                bf16x4 pkv;
#pragma unroll
                for (int i = 0; i < 4; ++i) pkv[i] = (bf16)exp2f(sv[cc][i]);
                *(bf16x4*)&Ps[pbase + ((cc * 2 + ph) ^ pk7) * 8 + plo] = pkv;
            }
        }

        // ---- phase B: PV + row-sum MFMAs for both strips ----
        __builtin_amdgcn_s_setprio(1);
#pragma unroll
        for (int p = 0; p < 2; ++p) {
            const int pbase = p ? pb1 : pb0;
#pragma unroll
            for (int kk = 0; kk < 2; ++kk) {
                bf16x8 ap = *(const bf16x8*)&Ps[pbase + ((kk * 4 + q8) ^ pk7) * 8];
#pragma unroll
                for (int ct = 0; ct < 2; ++ct)
                    o_acc[p][ct] = __builtin_amdgcn_mfma_f32_16x16x32_bf16(ap, vb[kk][ct], o_acc[p][ct], 0, 0, 0);
                l_acc[p] = __builtin_amdgcn_mfma_f32_16x16x32_bf16(ap, ones, l_acc[p], 0, 0, 0);
            }
        }
        __builtin_amdgcn_s_setprio(0);

        // counted wait: tile i+1's loads retired, tile i+2's may stay in
        // flight. Tail (no prefetch): full drain.
        if (pf) asm volatile("s_waitcnt vmcnt(2) lgkmcnt(0)" ::: "memory");
        else    asm volatile("s_waitcnt vmcnt(0) lgkmcnt(0)" ::: "memory");
        __builtin_amdgcn_s_barrier();
        __builtin_amdgcn_sched_barrier(0);
        cur = (cur == 2) ? 0 : cur + 1;
        stg = (stg == 2) ? 0 : stg + 1;
    }

    // epilogue: l_acc[p][i] IS the row-sum for t_local = q8*4+i
#pragma unroll
    for (int p = 0; p < 2; ++p)
#pragma unroll
        for (int i = 0; i < 4; ++i) {
            float inv = 1.0f / l_acc[p][i];
            int t = t0 + w * 32 + p * 16 + q8 * 4 + i;
#pragma unroll
            for (int ct = 0; ct < 2; ++ct) {
                int d = ct * 16 + r16;
                O[(size_t)t * 2048 + h * 128 + g * 32 + d] = (bf16)(o_acc[p][ct][i] * inv);
            }
        }

    // folded Wo conversion: each block converts its exact 4096-elem slice.
    {
        const int bid = blockIdx.y * 16 + blockIdx.x;   // gridDim.x == 16
#pragma unroll
        for (int it = 0; it < 2; ++it) {
            size_t off = (size_t)bid * 4096 + (size_t)it * 2048 + (size_t)tid * 8;
            stage8_f32(Wo + off, Wob + off);
        }
    }
}

// ---------------------------------------------------------------------------
// Contract: inputs fp32, output fp32. d_out doubles as scratch for xb/Wqb
// (dead before out_k64 writes). ws layout (12 MB used):
// Wlkb(1M) Wlvb(1M) Wob(4M) Qp(4M) LKp(1M) LVt(1M) bf16 elems.
// ---------------------------------------------------------------------------
extern "C" void kernel_launch(void* const* d_in, const int* in_sizes, int n_in,
                              void* d_out, int out_size, void* d_ws, size_t ws_size,
                              hipStream_t stream) {
    const float* x   = (const float*)d_in[0];
    const float* Wq  = (const float*)d_in[1];
    // d_in[2]=Wk, d_in[3]=Wv: computed-but-unused in the reference -> skipped
    const float* Wlk = (const float*)d_in[4];
    const float* Wlv = (const float*)d_in[5];
    const float* Wo  = (const float*)d_in[6];
    float* out = (float*)d_out;

    const size_t M4 = 4194304, M1 = 1048576;
    bf16* xb   = (bf16*)d_out;      // d_out scratch: dead before out_k64 writes
    bf16* Wqb  = xb + M4;
    bf16* p    = (bf16*)d_ws;
    bf16* Wlkb = p; p += M1;
    bf16* Wlvb = p; p += M1;
    bf16* Wob  = p; p += M4;
    bf16* Qp   = p; p += M4;
    bf16* LKp  = p; p += M1;
    bf16* LVt  = p;
    bf16* ATT  = Qp;                // alias: attn blocks read their own Q cells first

    cvt4c<<<dim3(5120), 256, 0, stream>>>(x, Wq, Wlk, Wlv,
                                          xb, Wqb, Wlkb, Wlvb);
    proj_k64<<<dim3(48, 16), 256, 0, stream>>>(xb, Wqb, Wlkb, Wlvb,
                                               Qp, LKp, LVt);
    attn7<<<dim3(16, 64), 256, 0, stream>>>(Qp, LKp, LVt, ATT, Wo, Wob);
    out_k64<<<dim3(32, 16), 256, 0, stream>>>(ATT, Wob, out);
}